// Round 1
// baseline (1977.963 us; speedup 1.0000x reference)
//
#include <hip/hip_runtime.h>
#include <math.h>

#define S 256
#define D 512
#define P 16
#define NIJ (D*D)
#define CAP 4096

__device__ __forceinline__ float gelu_f(float x){ return 0.5f*x*(1.f+erff(x*0.70710678118654752f)); }
__device__ __forceinline__ float silu_f(float x){ return x/(1.f+expf(-x)); }
__device__ __forceinline__ float sigm_f(float x){ return 1.f/(1.f+expf(-x)); }

// v[0..3] = flow values at linear elements e..e+3 (e multiple of 4): sum_p pw[p]*pat[p][e]
__device__ __forceinline__ void flow4(const float4* __restrict__ patv, const float* pws,
                                      int e, float v[4]){
  int base = e >> 2;
  float4 a = make_float4(0.f,0.f,0.f,0.f);
  #pragma unroll
  for (int p2=0;p2<16;++p2){
    float4 pv = patv[base + (p2<<16)];   // p*NIJ/4 = p*65536
    float w = pws[p2];
    a.x=fmaf(w,pv.x,a.x); a.y=fmaf(w,pv.y,a.y); a.z=fmaf(w,pv.z,a.z); a.w=fmaf(w,pv.w,a.w);
  }
  v[0]=a.x; v[1]=a.y; v[2]=a.z; v[3]=a.w;
}

// K1: LayerNorm + RoPE per row
__global__ void __launch_bounds__(256) k_ln_rope(const float* __restrict__ x,
    const float* __restrict__ g, const float* __restrict__ b,
    float* __restrict__ xn, float* __restrict__ xr){
  int s2 = blockIdx.x, tid = threadIdx.x;
  __shared__ float red[256];
  __shared__ float xnl[512];
  const float* xrow = x + s2*D;
  float v0 = xrow[tid], v1 = xrow[tid+256];
  red[tid] = v0+v1; __syncthreads();
  for (int st=128; st>0; st>>=1){ if (tid<st) red[tid]+=red[tid+st]; __syncthreads(); }
  float mean = red[0]*(1.f/512.f); __syncthreads();
  float d0=v0-mean, d1=v1-mean;
  red[tid]=d0*d0+d1*d1; __syncthreads();
  for (int st=128; st>0; st>>=1){ if (tid<st) red[tid]+=red[tid+st]; __syncthreads(); }
  float var = red[0]*(1.f/512.f);
  float rstd = rsqrtf(var+1e-5f);
  float a0 = d0*rstd*g[tid]+b[tid];
  float a1 = d1*rstd*g[tid+256]+b[tid+256];
  xn[s2*D+tid]=a0; xn[s2*D+tid+256]=a1;
  xnl[tid]=a0; xnl[tid+256]=a1;
  __syncthreads();
  int j = tid;                            // pair index 0..255
  float e = (float)(2*j)*(1.f/512.f);
  float inv = 1.f/powf(10000.f, e);
  float ang = (float)s2 * inv;
  float c = cosf(ang), sn = sinf(ang);
  float p0 = xnl[2*j], p1 = xnl[2*j+1];
  xr[s2*D+2*j]   = p0*c - p1*sn;
  xr[s2*D+2*j+1] = p1*c + p0*sn;
}

// K2: column means (mean over s of xr; mean over rows of memory_bank)
__global__ void __launch_bounds__(256) k_colmean(const float* __restrict__ xr,
    const float* __restrict__ bank, float* __restrict__ meanxr, float* __restrict__ memmean){
  int tid=threadIdx.x;
  if (blockIdx.x<2){
    int d2 = blockIdx.x*256+tid; float acc=0.f;
    for (int s2=0;s2<S;++s2) acc += xr[s2*D+d2];
    meanxr[d2]=acc*(1.f/256.f);
  } else {
    int d2=(blockIdx.x-2)*256+tid; float acc=0.f;
    for (int r=0;r<512;++r) acc += bank[r*D+d2];
    memmean[d2]=acc*(1.f/512.f);
  }
}

// K3: window MLP -> kk; fold ctx/mem halves into effective biases
__global__ void __launch_bounds__(256) k_head(const float* __restrict__ meanxr, const float* __restrict__ memmean,
    const float* __restrict__ ww1, const float* __restrict__ wb1,
    const float* __restrict__ ww2, const float* __restrict__ wb2,
    const float* __restrict__ sw1, const float* __restrict__ sb1,
    const float* __restrict__ iw1, const float* __restrict__ ib1,
    const float* __restrict__ mw1, const float* __restrict__ mb1,
    float* __restrict__ ctxsel, float* __restrict__ ctxint,
    float* __restrict__ mempart, int* __restrict__ kkout){
  int tid=threadIdx.x;
  __shared__ float mx[512], mm[512], gw[64];
  mx[tid]=meanxr[tid]; mx[tid+256]=meanxr[tid+256];
  mm[tid]=memmean[tid]; mm[tid+256]=memmean[tid+256];
  __syncthreads();
  if (tid<64){ float a=wb1[tid]; for (int d2=0;d2<512;++d2) a=fmaf(mx[d2], ww1[d2*64+tid], a); gw[tid]=gelu_f(a); }
  __syncthreads();
  if (tid==0){
    float a=wb2[0]; for (int h=0;h<64;++h) a=fmaf(gw[h], ww2[h], a);
    float win = sigm_f(a)*3840.f+256.f;
    float asp = 0.1f*(win*(1.f/4096.f));
    float t = 262144.f*asp;
    int kk=(int)t; if (kk<1) kk=1;
    *kkout=kk;
  }
  if (tid<32){ float a=sb1[tid]; for (int d2=0;d2<512;++d2) a=fmaf(mx[d2], sw1[(512+d2)*32+tid], a); ctxsel[tid]=a; }
  if (tid>=64 && tid<128){ int o=tid-64; float a=ib1[o]; for (int d2=0;d2<512;++d2) a=fmaf(mx[d2], iw1[(512+d2)*64+o], a); ctxint[o]=a; }
  for (int o=tid;o<512;o+=256){ float a=mb1[o]; for (int d2=0;d2<512;++d2) a=fmaf(mm[d2], mw1[(512+d2)*512+o], a); mempart[o]=a; }
}

// K4: per-position selection MLP (softmax pw) + intensity
__global__ void __launch_bounds__(256) k_selint(const float* __restrict__ xr,
    const float* __restrict__ ctxsel, const float* __restrict__ ctxint,
    const float* __restrict__ sw1, const float* __restrict__ sw2, const float* __restrict__ sb2,
    const float* __restrict__ iw1, const float* __restrict__ iw2, const float* __restrict__ ib2,
    float* __restrict__ pw, float* __restrict__ inten){
  int s2=blockIdx.x, tid=threadIdx.x;
  __shared__ float xl[512]; __shared__ float h1[32], h2[64], lg[16];
  xl[tid]=xr[s2*D+tid]; xl[tid+256]=xr[s2*D+tid+256];
  __syncthreads();
  if (tid<32){ float a=ctxsel[tid]; for (int d2=0;d2<512;++d2) a=fmaf(xl[d2], sw1[d2*32+tid], a); h1[tid]=gelu_f(a); }
  else if (tid<96){ int o=tid-32; float a=ctxint[o]; for (int d2=0;d2<512;++d2) a=fmaf(xl[d2], iw1[d2*64+o], a); h2[o]=gelu_f(a); }
  __syncthreads();
  if (tid<16){ float a=sb2[tid]; for (int h=0;h<32;++h) a=fmaf(h1[h], sw2[h*16+tid], a); lg[tid]=a; }
  __syncthreads();
  if (tid==0){
    float m=lg[0]; for (int p2=1;p2<16;++p2) m=fmaxf(m,lg[p2]);
    float sm=0.f; float e[16];
    for (int p2=0;p2<16;++p2){ e[p2]=expf(lg[p2]-m); sm+=e[p2]; }
    float r=1.f/sm;
    for (int p2=0;p2<16;++p2) pw[s2*16+p2]=e[p2]*r;
  }
  if (tid==64){ float a=ib2[0]; for (int h=0;h<64;++h) a=fmaf(h2[h], iw2[h], a); inten[s2]=sigm_f(a); }
}

// K5: per-position 14-bit histogram of |flow| bit patterns -> (bin, rank-in-bin, bin count)
__global__ void __launch_bounds__(256) k_hist(const float* __restrict__ pat, const float* __restrict__ pw,
    const int* __restrict__ kkin, unsigned* __restrict__ meta){
  int s2=blockIdx.x, tid=threadIdx.x;
  __shared__ unsigned hist[16384];
  __shared__ float pws[16];
  __shared__ unsigned part[256];
  for (int i=tid;i<16384;i+=256) hist[i]=0u;
  if (tid<16) pws[tid]=pw[s2*16+tid];
  __syncthreads();
  const float4* patv=(const float4*)pat;
  for (int e2=tid*4; e2<NIJ; e2+=1024){
    float v[4]; flow4(patv, pws, e2, v);
    #pragma unroll
    for (int q=0;q<4;++q){
      unsigned bits=__float_as_uint(v[q])&0x7fffffffu;
      atomicAdd(&hist[bits>>17],1u);
    }
  }
  __syncthreads();
  unsigned ps=0;
  for (int k2=0;k2<64;++k2) ps+=hist[tid*64+k2];
  part[tid]=ps;
  __syncthreads();
  if (tid==0){
    unsigned kk=(unsigned)(*kkin);
    unsigned cum=0; int seg=0; unsigned r=kk;
    for (int t=255;t>=0;--t){ if (cum+part[t]>=kk){ seg=t; r=kk-cum; break; } cum+=part[t]; }
    unsigned cum2=0; int bstar=seg*64;
    for (int b2=seg*64+63;b2>=seg*64;--b2){ if (cum2+hist[b2]>=r){ bstar=b2; r=r-cum2; break; } cum2+=hist[b2]; }
    meta[s2*3+0]=(unsigned)bstar; meta[s2*3+1]=r; meta[s2*3+2]=hist[bstar];
  }
}

// K6: masked matvec with exact threshold refinement + residual + LayerNorm2 -> co
__global__ void __launch_bounds__(256) k_select(const float* __restrict__ pat, const float* __restrict__ pw,
    const float* __restrict__ xn, const float* __restrict__ x,
    const float* __restrict__ inten, const unsigned* __restrict__ meta,
    const float* __restrict__ n2g, const float* __restrict__ n2b,
    float* __restrict__ co){
  int s2=blockIdx.x, tid=threadIdx.x;
  __shared__ float xnl[512], outr[512], pws[16];
  __shared__ unsigned cbits[CAP]; __shared__ float ccon[CAP]; __shared__ unsigned short crow_[CAP];
  __shared__ unsigned ccount; __shared__ unsigned rhist[2048]; __shared__ unsigned thsh[2];
  __shared__ float red[256];
  xnl[tid]=xn[s2*D+tid]; xnl[tid+256]=xn[s2*D+tid+256];
  outr[tid]=0.f; outr[tid+256]=0.f;
  if (tid<16) pws[tid]=pw[s2*16+tid];
  if (tid==0) ccount=0u;
  unsigned bstar=meta[s2*3+0], rnk=meta[s2*3+1], cnt=meta[s2*3+2];
  bool incl = cnt>CAP;   // pathological fallback: keep whole bin
  __syncthreads();
  const float4* patv=(const float4*)pat;
  int wave=tid>>6, lane=tid&63;
  for (int i=wave;i<512;i+=4){
    float acc=0.f;
    #pragma unroll
    for (int jc=0;jc<2;++jc){
      int j=(lane<<2)+(jc<<8);
      float v[4]; flow4(patv, pws, (i<<9)+j, v);
      #pragma unroll
      for (int q=0;q<4;++q){
        unsigned bits=__float_as_uint(v[q])&0x7fffffffu;
        unsigned pfx=bits>>17;
        if (pfx>bstar || (incl && pfx==bstar)) acc=fmaf(v[q], xnl[j+q], acc);
        else if (pfx==bstar){
          unsigned idx=atomicAdd(&ccount,1u);
          if (idx<CAP){ cbits[idx]=bits; ccon[idx]=v[q]*xnl[j+q]; crow_[idx]=(unsigned short)i; }
        }
      }
    }
    #pragma unroll
    for (int m=32;m>0;m>>=1) acc += __shfl_xor(acc, m, 64);
    if (lane==0) outr[i]=acc;
  }
  __syncthreads();
  if (!incl){
    unsigned n=ccount; if (n>CAP) n=CAP;
    for (int i=tid;i<2048;i+=256) rhist[i]=0u;
    __syncthreads();
    for (unsigned c=tid;c<n;c+=256) atomicAdd(&rhist[(cbits[c]>>6)&0x7ffu],1u);
    __syncthreads();
    if (tid==0){
      unsigned cum=0, r2=rnk; int sub=0;
      for (int b2=2047;b2>=0;--b2){ if (cum+rhist[b2]>=rnk){ sub=b2; r2=rnk-cum; break; } cum+=rhist[b2]; }
      thsh[0]=(unsigned)sub; thsh[1]=r2;
    }
    __syncthreads();
    unsigned sub=thsh[0], r2=thsh[1];
    if (tid<64) rhist[tid]=0u;
    __syncthreads();
    for (unsigned c=tid;c<n;c+=256) if (((cbits[c]>>6)&0x7ffu)==sub) atomicAdd(&rhist[cbits[c]&63u],1u);
    __syncthreads();
    if (tid==0){
      unsigned cum=0; int lo=0;
      for (int b2=63;b2>=0;--b2){ if (cum+rhist[b2]>=r2){ lo=b2; break; } cum+=rhist[b2]; }
      thsh[0]=(bstar<<17)|(sub<<6)|(unsigned)lo;
    }
    __syncthreads();
    unsigned thb=thsh[0];
    for (unsigned c=tid;c<n;c+=256) if (cbits[c]>=thb) atomicAdd(&outr[crow_[c]], ccon[c]);
    __syncthreads();
  }
  float it=inten[s2];
  float t0=x[s2*D+tid]+outr[tid]*it;
  float t1=x[s2*D+tid+256]+outr[tid+256]*it;
  red[tid]=t0+t1; __syncthreads();
  for (int st=128;st>0;st>>=1){ if (tid<st) red[tid]+=red[tid+st]; __syncthreads(); }
  float mean=red[0]*(1.f/512.f); __syncthreads();
  float d0=t0-mean, d1=t1-mean;
  red[tid]=d0*d0+d1*d1; __syncthreads();
  for (int st=128;st>0;st>>=1){ if (tid<st) red[tid]+=red[tid+st]; __syncthreads(); }
  float var=red[0]*(1.f/512.f);
  float rstd=rsqrtf(var+1e-5f);
  co[s2*D+tid]=d0*rstd*n2g[tid]+n2b[tid];
  co[s2*D+tid+256]=d1*rstd*n2g[tid+256]+n2b[tid+256];
}

// Generic f32 GEMM: C[256,N] = act(A[256,K] @ W[K,N] + bias) (+ res)
template<int ACT, int RES>
__global__ void __launch_bounds__(256) k_gemm(const float* __restrict__ A, const float* __restrict__ W,
    const float* __restrict__ bias, const float* __restrict__ res,
    float* __restrict__ C, int K, int N){
  __shared__ float As[32][64];
  int tid=threadIdx.x;
  int col=(blockIdx.x<<6)+(tid&63);
  int rg=tid>>6;
  int s0=blockIdx.y<<5;
  float acc[8]={0.f,0.f,0.f,0.f,0.f,0.f,0.f,0.f};
  for (int k0=0;k0<K;k0+=64){
    for (int idx=tid;idx<2048;idx+=256) As[idx>>6][idx&63]=A[(s0+(idx>>6))*K + k0 + (idx&63)];
    __syncthreads();
    for (int kk=0;kk<64;++kk){
      float w=W[(k0+kk)*N+col];
      #pragma unroll
      for (int r8=0;r8<8;++r8) acc[r8]=fmaf(As[(rg<<3)+r8][kk], w, acc[r8]);
    }
    __syncthreads();
  }
  float bb=bias[col];
  #pragma unroll
  for (int r8=0;r8<8;++r8){
    int row=s0+(rg<<3)+r8;
    float v=acc[r8]+bb;
    if (ACT==1) v=gelu_f(v);
    if (ACT==2) v=silu_f(v);
    if (RES) v+=res[row*N+col];
    C[row*N+col]=v;
  }
}

// gated FFN elementwise: gv = silu(gate)*val
__global__ void __launch_bounds__(256) k_gate(const float* __restrict__ ff, float* __restrict__ gv){
  int idx=blockIdx.x*256+threadIdx.x;
  if (idx<S*2048){
    int s2=idx>>11, m=idx&2047;
    float g=ff[s2*4096+m], v=ff[s2*4096+2048+m];
    gv[idx]=silu_f(g)*v;
  }
}

extern "C" void kernel_launch(void* const* d_in, const int* in_sizes, int n_in,
                              void* d_out, int out_size, void* d_ws, size_t ws_size,
                              hipStream_t stream){
  const float* x   =(const float*)d_in[0];
  const float* pat =(const float*)d_in[1];
  const float* sw1 =(const float*)d_in[2];
  const float* sb1 =(const float*)d_in[3];
  const float* sw2 =(const float*)d_in[4];
  const float* sb2 =(const float*)d_in[5];
  const float* ww1 =(const float*)d_in[6];
  const float* wb1 =(const float*)d_in[7];
  const float* ww2 =(const float*)d_in[8];
  const float* wb2 =(const float*)d_in[9];
  const float* iw1 =(const float*)d_in[10];
  const float* ib1 =(const float*)d_in[11];
  const float* iw2 =(const float*)d_in[12];
  const float* ib2 =(const float*)d_in[13];
  const float* mw1 =(const float*)d_in[14];
  const float* mb1 =(const float*)d_in[15];
  const float* mw2 =(const float*)d_in[16];
  const float* mb2 =(const float*)d_in[17];
  const float* bank=(const float*)d_in[18];
  const float* upw =(const float*)d_in[19];
  const float* upb =(const float*)d_in[20];
  const float* dww =(const float*)d_in[21];
  const float* dwb =(const float*)d_in[22];
  const float* n1g =(const float*)d_in[23];
  const float* n1b =(const float*)d_in[24];
  const float* n2g =(const float*)d_in[25];
  const float* n2b =(const float*)d_in[26];
  float* out=(float*)d_out;

  float* w = (float*)d_ws;
  float* xn     = w;                 // 131072
  float* xr     = xn+131072;         // 131072
  float* meanxr = xr+131072;         // 512
  float* memmean= meanxr+512;        // 512
  float* pwb    = memmean+512;       // 4096
  float* inten  = pwb+4096;          // 256
  float* ctxsel = inten+256;         // 32
  float* ctxint = ctxsel+32;         // 64
  float* mempart= ctxint+64;         // 512
  float* co     = mempart+512;       // 131072
  float* h1     = co+131072;         // 131072
  float* co2    = h1+131072;         // 131072
  float* ff     = co2+131072;        // 1048576
  float* gv     = ff+1048576;        // 524288
  int*   kkp    = (int*)(gv+524288);
  unsigned* meta= (unsigned*)(kkp+4);  // 256*3

  k_ln_rope<<<S,256,0,stream>>>(x,n1g,n1b,xn,xr);
  k_colmean<<<4,256,0,stream>>>(xr,bank,meanxr,memmean);
  k_head<<<1,256,0,stream>>>(meanxr,memmean,ww1,wb1,ww2,wb2,sw1,sb1,iw1,ib1,mw1,mb1,
                             ctxsel,ctxint,mempart,kkp);
  k_selint<<<S,256,0,stream>>>(xr,ctxsel,ctxint,sw1,sw2,sb2,iw1,iw2,ib2,pwb,inten);
  k_hist<<<S,256,0,stream>>>(pat,pwb,kkp,meta);
  k_select<<<S,256,0,stream>>>(pat,pwb,xn,x,inten,meta,n2g,n2b,co);
  k_gemm<2,0><<<dim3(8,8),256,0,stream>>>(co, mw1, mempart, nullptr, h1, 512, 512);
  k_gemm<0,1><<<dim3(8,8),256,0,stream>>>(h1, mw2, mb2, co, co2, 512, 512);
  k_gemm<0,0><<<dim3(64,8),256,0,stream>>>(co2, upw, upb, nullptr, ff, 512, 4096);
  k_gate<<<2048,256,0,stream>>>(ff,gv);
  k_gemm<0,1><<<dim3(8,8),256,0,stream>>>(gv, dww, dwb, co2, out, 2048, 512);
}

// Round 3
// 1093.016 us; speedup vs baseline: 1.8096x; 1.8096x over previous
//
#include <hip/hip_runtime.h>
#include <math.h>

#define S 256
#define D 512
#define P 16
#define NIJ (D*D)
#define CAP 4096
#define TCAP 4096

__device__ __forceinline__ float gelu_f(float x){ return 0.5f*x*(1.f+erff(x*0.70710678118654752f)); }
__device__ __forceinline__ float silu_f(float x){ return x/(1.f+expf(-x)); }
__device__ __forceinline__ float sigm_f(float x){ return 1.f/(1.f+expf(-x)); }

// v[0..3] = flow values at linear elements e..e+3 (e multiple of 4): sum_p pw[p]*pat[p][e]
__device__ __forceinline__ void flow4(const float4* __restrict__ patv, const float* pws,
                                      int e, float v[4]){
  int base = e >> 2;
  float4 a = make_float4(0.f,0.f,0.f,0.f);
  #pragma unroll
  for (int p2=0;p2<16;++p2){
    float4 pv = patv[base + (p2<<16)];
    float w = pws[p2];
    a.x=fmaf(w,pv.x,a.x); a.y=fmaf(w,pv.y,a.y); a.z=fmaf(w,pv.z,a.z); a.w=fmaf(w,pv.w,a.w);
  }
  v[0]=a.x; v[1]=a.y; v[2]=a.z; v[3]=a.w;
}

// K1: LayerNorm + RoPE per row
__global__ void __launch_bounds__(256) k_ln_rope(const float* __restrict__ x,
    const float* __restrict__ g, const float* __restrict__ b,
    float* __restrict__ xn, float* __restrict__ xr){
  int s2 = blockIdx.x, tid = threadIdx.x;
  __shared__ float red[256];
  __shared__ float xnl[512];
  const float* xrow = x + s2*D;
  float v0 = xrow[tid], v1 = xrow[tid+256];
  red[tid] = v0+v1; __syncthreads();
  for (int st=128; st>0; st>>=1){ if (tid<st) red[tid]+=red[tid+st]; __syncthreads(); }
  float mean = red[0]*(1.f/512.f); __syncthreads();
  float d0=v0-mean, d1=v1-mean;
  red[tid]=d0*d0+d1*d1; __syncthreads();
  for (int st=128; st>0; st>>=1){ if (tid<st) red[tid]+=red[tid+st]; __syncthreads(); }
  float var = red[0]*(1.f/512.f);
  float rstd = rsqrtf(var+1e-5f);
  float a0 = d0*rstd*g[tid]+b[tid];
  float a1 = d1*rstd*g[tid+256]+b[tid+256];
  xn[s2*D+tid]=a0; xn[s2*D+tid+256]=a1;
  xnl[tid]=a0; xnl[tid+256]=a1;
  __syncthreads();
  int j = tid;
  float e = (float)(2*j)*(1.f/512.f);
  float inv = 1.f/powf(10000.f, e);
  float ang = (float)s2 * inv;
  float c = cosf(ang), sn = sinf(ang);
  float p0 = xnl[2*j], p1 = xnl[2*j+1];
  xr[s2*D+2*j]   = p0*c - p1*sn;
  xr[s2*D+2*j+1] = p1*c + p0*sn;
}

// K2: column means
__global__ void __launch_bounds__(256) k_colmean(const float* __restrict__ xr,
    const float* __restrict__ bank, float* __restrict__ meanxr, float* __restrict__ memmean){
  int tid=threadIdx.x;
  if (blockIdx.x<2){
    int d2 = blockIdx.x*256+tid; float acc=0.f;
    for (int s2=0;s2<S;++s2) acc += xr[s2*D+d2];
    meanxr[d2]=acc*(1.f/256.f);
  } else {
    int d2=(blockIdx.x-2)*256+tid; float acc=0.f;
    for (int r=0;r<512;++r) acc += bank[r*D+d2];
    memmean[d2]=acc*(1.f/512.f);
  }
}

// K3: window MLP -> kk; fold ctx/mem halves into effective biases
__global__ void __launch_bounds__(256) k_head(const float* __restrict__ meanxr, const float* __restrict__ memmean,
    const float* __restrict__ ww1, const float* __restrict__ wb1,
    const float* __restrict__ ww2, const float* __restrict__ wb2,
    const float* __restrict__ sw1, const float* __restrict__ sb1,
    const float* __restrict__ iw1, const float* __restrict__ ib1,
    const float* __restrict__ mw1, const float* __restrict__ mb1,
    float* __restrict__ ctxsel, float* __restrict__ ctxint,
    float* __restrict__ mempart, int* __restrict__ kkout){
  int tid=threadIdx.x;
  __shared__ float mx[512], mm[512], gw[64];
  mx[tid]=meanxr[tid]; mx[tid+256]=meanxr[tid+256];
  mm[tid]=memmean[tid]; mm[tid+256]=memmean[tid+256];
  __syncthreads();
  if (tid<64){ float a=wb1[tid]; for (int d2=0;d2<512;++d2) a=fmaf(mx[d2], ww1[d2*64+tid], a); gw[tid]=gelu_f(a); }
  __syncthreads();
  if (tid==0){
    float a=wb2[0]; for (int h=0;h<64;++h) a=fmaf(gw[h], ww2[h], a);
    float win = sigm_f(a)*3840.f+256.f;
    float asp = 0.1f*(win*(1.f/4096.f));
    float t = 262144.f*asp;
    int kk=(int)t; if (kk<1) kk=1;
    *kkout=kk;
  }
  if (tid<32){ float a=sb1[tid]; for (int d2=0;d2<512;++d2) a=fmaf(mx[d2], sw1[(512+d2)*32+tid], a); ctxsel[tid]=a; }
  if (tid>=64 && tid<128){ int o=tid-64; float a=ib1[o]; for (int d2=0;d2<512;++d2) a=fmaf(mx[d2], iw1[(512+d2)*64+o], a); ctxint[o]=a; }
  for (int o=tid;o<512;o+=256){ float a=mb1[o]; for (int d2=0;d2<512;++d2) a=fmaf(mm[d2], mw1[(512+d2)*512+o], a); mempart[o]=a; }
}

// K4: per-position selection MLP (softmax pw) + intensity
__global__ void __launch_bounds__(256) k_selint(const float* __restrict__ xr,
    const float* __restrict__ ctxsel, const float* __restrict__ ctxint,
    const float* __restrict__ sw1, const float* __restrict__ sw2, const float* __restrict__ sb2,
    const float* __restrict__ iw1, const float* __restrict__ iw2, const float* __restrict__ ib2,
    float* __restrict__ pw, float* __restrict__ inten){
  int s2=blockIdx.x, tid=threadIdx.x;
  __shared__ float xl[512]; __shared__ float h1[32], h2[64], lg[16];
  xl[tid]=xr[s2*D+tid]; xl[tid+256]=xr[s2*D+tid+256];
  __syncthreads();
  if (tid<32){ float a=ctxsel[tid]; for (int d2=0;d2<512;++d2) a=fmaf(xl[d2], sw1[d2*32+tid], a); h1[tid]=gelu_f(a); }
  else if (tid<96){ int o=tid-32; float a=ctxint[o]; for (int d2=0;d2<512;++d2) a=fmaf(xl[d2], iw1[d2*64+o], a); h2[o]=gelu_f(a); }
  __syncthreads();
  if (tid<16){ float a=sb2[tid]; for (int h=0;h<32;++h) a=fmaf(h1[h], sw2[h*16+tid], a); lg[tid]=a; }
  __syncthreads();
  if (tid==0){
    float m=lg[0]; for (int p2=1;p2<16;++p2) m=fmaxf(m,lg[p2]);
    float sm=0.f; float e[16];
    for (int p2=0;p2<16;++p2){ e[p2]=expf(lg[p2]-m); sm+=e[p2]; }
    float r=1.f/sm;
    for (int p2=0;p2<16;++p2) pw[s2*16+p2]=e[p2]*r;
  }
  if (tid==64){ float a=ib2[0]; for (int h=0;h<64;++h) a=fmaf(h2[h], iw2[h], a); inten[s2]=sigm_f(a); }
}

// ---------------- FAST PATH (large ws): materialize flow ----------------

// k_flow_store: grid (32 chunks, 32 groups). Each block: 8 positions x 8192 elems.
__global__ void __launch_bounds__(256) k_flow_store(const float* __restrict__ pat,
    const float* __restrict__ pw, float* __restrict__ flow){
  int c=blockIdx.x, g=blockIdx.y, tid=threadIdx.x;
  __shared__ float ws[128];
  if (tid<128) ws[tid]=pw[(g<<3)*16 + tid];
  __syncthreads();
  const float4* patv=(const float4*)pat;
  float4* fout=(float4*)flow;
  for (int s=0;s<8;++s){
    int f4=(c<<11)+(s<<8)+tid;
    float4 pv[16];
    #pragma unroll
    for (int p2=0;p2<16;++p2) pv[p2]=patv[(p2<<16)+f4];
    #pragma unroll
    for (int pos=0;pos<8;++pos){
      float4 a=make_float4(0.f,0.f,0.f,0.f);
      #pragma unroll
      for (int p2=0;p2<16;++p2){
        float w=ws[(pos<<4)+p2];
        a.x=fmaf(w,pv[p2].x,a.x); a.y=fmaf(w,pv[p2].y,a.y);
        a.z=fmaf(w,pv[p2].z,a.z); a.w=fmaf(w,pv[p2].w,a.w);
      }
      fout[(size_t)((g<<3)+pos)*65536 + f4]=a;
    }
  }
}

// k_topk: fused histogram + exact-threshold select + matvec + residual + LN2
__global__ void __launch_bounds__(256) k_topk(const float* __restrict__ flow,
    const float* __restrict__ xn, const float* __restrict__ x,
    const float* __restrict__ inten, const int* __restrict__ kkin,
    const float* __restrict__ n2g, const float* __restrict__ n2b,
    float* __restrict__ co){
  int s2=blockIdx.x, tid=threadIdx.x;
  __shared__ unsigned hist[8192];         // 32KB; reused: cbits[0..4095], ccon[4096..8191]
  __shared__ unsigned short crow_[TCAP];  // 8KB
  __shared__ unsigned rhist[2048];        // 8KB
  __shared__ float xnl[512], outr[512], red[256];
  __shared__ unsigned part[256];
  __shared__ unsigned thsh[4];
  __shared__ unsigned ccount;
  xnl[tid]=xn[s2*D+tid]; xnl[tid+256]=xn[s2*D+tid+256];
  outr[tid]=0.f; outr[tid+256]=0.f;
  for (int i=tid;i<8192;i+=256) hist[i]=0u;
  if (tid==0) ccount=0u;
  __syncthreads();
  const float4* fv=(const float4*)(flow + (size_t)s2*NIJ);
  // phase A: 13-bit prefix histogram
  for (int s=0;s<256;++s){
    float4 v=fv[s*256+tid];
    atomicAdd(&hist[(__float_as_uint(v.x)&0x7fffffffu)>>18],1u);
    atomicAdd(&hist[(__float_as_uint(v.y)&0x7fffffffu)>>18],1u);
    atomicAdd(&hist[(__float_as_uint(v.z)&0x7fffffffu)>>18],1u);
    atomicAdd(&hist[(__float_as_uint(v.w)&0x7fffffffu)>>18],1u);
  }
  __syncthreads();
  unsigned ps=0;
  for (int k2=0;k2<32;++k2) ps+=hist[tid*32+k2];
  part[tid]=ps; __syncthreads();
  if (tid==0){
    unsigned kk=(unsigned)(*kkin);
    unsigned cum=0; int seg=0; unsigned r=kk;
    for (int t=255;t>=0;--t){ if (cum+part[t]>=kk){ seg=t; r=kk-cum; break; } cum+=part[t]; }
    unsigned cum2=0; unsigned bst=seg*32;
    for (int b2=seg*32+31;b2>=seg*32;--b2){ if (cum2+hist[b2]>=r){ bst=(unsigned)b2; r=r-cum2; break; } cum2+=hist[b2]; }
    thsh[0]=bst; thsh[1]=r; thsh[2]=hist[bst];
  }
  __syncthreads();
  unsigned bstar=thsh[0], rnk=thsh[1], cnt=thsh[2];
  bool incl = cnt>TCAP;
  __syncthreads();
  // phase C: masked accumulate + candidate stash (reuses hist region)
  unsigned* cbits=hist; float* ccon=(float*)(hist+4096);
  for (int s=0;s<256;++s){
    int f4=s*256+tid;
    float4 v=fv[f4];
    int e=f4*4;
    float vv[4]={v.x,v.y,v.z,v.w};
    #pragma unroll
    for (int q=0;q<4;++q){
      float val=vv[q];
      unsigned bits=__float_as_uint(val)&0x7fffffffu;
      unsigned pfx=bits>>18;
      int ee=e+q, row=ee>>9, colj=ee&511;
      if (pfx>bstar || (incl && pfx==bstar)) atomicAdd(&outr[row], val*xnl[colj]);
      else if (pfx==bstar){
        unsigned idx=atomicAdd(&ccount,1u);
        if (idx<TCAP){ cbits[idx]=bits; ccon[idx]=val*xnl[colj]; crow_[idx]=(unsigned short)row; }
      }
    }
  }
  __syncthreads();
  if (!incl){
    unsigned n=ccount; if (n>TCAP) n=TCAP;
    for (int i=tid;i<2048;i+=256) rhist[i]=0u;
    __syncthreads();
    for (unsigned c2=tid;c2<n;c2+=256) atomicAdd(&rhist[(cbits[c2]>>7)&0x7ffu],1u);
    __syncthreads();
    if (tid==0){
      unsigned cum=0,r2=rnk; int sub=0;
      for (int b2=2047;b2>=0;--b2){ if (cum+rhist[b2]>=rnk){ sub=b2; r2=rnk-cum; break; } cum+=rhist[b2]; }
      thsh[0]=(unsigned)sub; thsh[1]=r2;
    }
    __syncthreads();
    unsigned sub=thsh[0], r2=thsh[1];
    if (tid<128) rhist[tid]=0u;
    __syncthreads();
    for (unsigned c2=tid;c2<n;c2+=256) if (((cbits[c2]>>7)&0x7ffu)==sub) atomicAdd(&rhist[cbits[c2]&127u],1u);
    __syncthreads();
    if (tid==0){
      unsigned cum=0; unsigned lo=0;
      for (int b2=127;b2>=0;--b2){ if (cum+rhist[b2]>=r2){ lo=(unsigned)b2; break; } cum+=rhist[b2]; }
      thsh[2]=(bstar<<18)|(sub<<7)|lo;
    }
    __syncthreads();
    unsigned thb=thsh[2];
    for (unsigned c2=tid;c2<n;c2+=256) if (cbits[c2]>=thb) atomicAdd(&outr[crow_[c2]], ccon[c2]);
  }
  __syncthreads();
  float it=inten[s2];
  float t0=x[s2*D+tid]+outr[tid]*it;
  float t1=x[s2*D+tid+256]+outr[tid+256]*it;
  red[tid]=t0+t1; __syncthreads();
  for (int st=128;st>0;st>>=1){ if (tid<st) red[tid]+=red[tid+st]; __syncthreads(); }
  float mean=red[0]*(1.f/512.f); __syncthreads();
  float d0=t0-mean, d1=t1-mean;
  red[tid]=d0*d0+d1*d1; __syncthreads();
  for (int st=128;st>0;st>>=1){ if (tid<st) red[tid]+=red[tid+st]; __syncthreads(); }
  float var=red[0]*(1.f/512.f);
  float rstd=rsqrtf(var+1e-5f);
  co[s2*D+tid]=d0*rstd*n2g[tid]+n2b[tid];
  co[s2*D+tid+256]=d1*rstd*n2g[tid+256]+n2b[tid+256];
}

// ---------------- FALLBACK PATH (small ws): recompute flow ----------------

__global__ void __launch_bounds__(256) k_hist(const float* __restrict__ pat, const float* __restrict__ pw,
    const int* __restrict__ kkin, unsigned* __restrict__ meta){
  int s2=blockIdx.x, tid=threadIdx.x;
  __shared__ unsigned hist[16384];
  __shared__ float pws[16];
  __shared__ unsigned part[256];
  for (int i=tid;i<16384;i+=256) hist[i]=0u;
  if (tid<16) pws[tid]=pw[s2*16+tid];
  __syncthreads();
  const float4* patv=(const float4*)pat;
  for (int e2=tid*4; e2<NIJ; e2+=1024){
    float v[4]; flow4(patv, pws, e2, v);
    #pragma unroll
    for (int q=0;q<4;++q){
      unsigned bits=__float_as_uint(v[q])&0x7fffffffu;
      atomicAdd(&hist[bits>>17],1u);
    }
  }
  __syncthreads();
  unsigned ps=0;
  for (int k2=0;k2<64;++k2) ps+=hist[tid*64+k2];
  part[tid]=ps;
  __syncthreads();
  if (tid==0){
    unsigned kk=(unsigned)(*kkin);
    unsigned cum=0; int seg=0; unsigned r=kk;
    for (int t=255;t>=0;--t){ if (cum+part[t]>=kk){ seg=t; r=kk-cum; break; } cum+=part[t]; }
    unsigned cum2=0; int bstar=seg*64;
    for (int b2=seg*64+63;b2>=seg*64;--b2){ if (cum2+hist[b2]>=r){ bstar=b2; r=r-cum2; break; } cum2+=hist[b2]; }
    meta[s2*3+0]=(unsigned)bstar; meta[s2*3+1]=r; meta[s2*3+2]=hist[bstar];
  }
}

__global__ void __launch_bounds__(256) k_select(const float* __restrict__ pat, const float* __restrict__ pw,
    const float* __restrict__ xn, const float* __restrict__ x,
    const float* __restrict__ inten, const unsigned* __restrict__ meta,
    const float* __restrict__ n2g, const float* __restrict__ n2b,
    float* __restrict__ co){
  int s2=blockIdx.x, tid=threadIdx.x;
  __shared__ float xnl[512], outr[512], pws[16];
  __shared__ unsigned cbits[CAP]; __shared__ float ccon[CAP]; __shared__ unsigned short crow_[CAP];
  __shared__ unsigned ccount; __shared__ unsigned rhist[2048]; __shared__ unsigned thsh[2];
  __shared__ float red[256];
  xnl[tid]=xn[s2*D+tid]; xnl[tid+256]=xn[s2*D+tid+256];
  outr[tid]=0.f; outr[tid+256]=0.f;
  if (tid<16) pws[tid]=pw[s2*16+tid];
  if (tid==0) ccount=0u;
  unsigned bstar=meta[s2*3+0], rnk=meta[s2*3+1], cnt=meta[s2*3+2];
  bool incl = cnt>CAP;
  __syncthreads();
  const float4* patv=(const float4*)pat;
  int wave=tid>>6, lane=tid&63;
  for (int i=wave;i<512;i+=4){
    float acc=0.f;
    #pragma unroll
    for (int jc=0;jc<2;++jc){
      int j=(lane<<2)+(jc<<8);
      float v[4]; flow4(patv, pws, (i<<9)+j, v);
      #pragma unroll
      for (int q=0;q<4;++q){
        unsigned bits=__float_as_uint(v[q])&0x7fffffffu;
        unsigned pfx=bits>>17;
        if (pfx>bstar || (incl && pfx==bstar)) acc=fmaf(v[q], xnl[j+q], acc);
        else if (pfx==bstar){
          unsigned idx=atomicAdd(&ccount,1u);
          if (idx<CAP){ cbits[idx]=bits; ccon[idx]=v[q]*xnl[j+q]; crow_[idx]=(unsigned short)i; }
        }
      }
    }
    #pragma unroll
    for (int m=32;m>0;m>>=1) acc += __shfl_xor(acc, m, 64);
    if (lane==0) outr[i]=acc;
  }
  __syncthreads();
  if (!incl){
    unsigned n=ccount; if (n>CAP) n=CAP;
    for (int i=tid;i<2048;i+=256) rhist[i]=0u;
    __syncthreads();
    for (unsigned c=tid;c<n;c+=256) atomicAdd(&rhist[(cbits[c]>>6)&0x7ffu],1u);
    __syncthreads();
    if (tid==0){
      unsigned cum=0, r2=rnk; int sub=0;
      for (int b2=2047;b2>=0;--b2){ if (cum+rhist[b2]>=rnk){ sub=b2; r2=rnk-cum; break; } cum+=rhist[b2]; }
      thsh[0]=(unsigned)sub; thsh[1]=r2;
    }
    __syncthreads();
    unsigned sub=thsh[0], r2=thsh[1];
    if (tid<64) rhist[tid]=0u;
    __syncthreads();
    for (unsigned c=tid;c<n;c+=256) if (((cbits[c]>>6)&0x7ffu)==sub) atomicAdd(&rhist[cbits[c]&63u],1u);
    __syncthreads();
    if (tid==0){
      unsigned cum=0; int lo=0;
      for (int b2=63;b2>=0;--b2){ if (cum+rhist[b2]>=r2){ lo=b2; break; } cum+=rhist[b2]; }
      thsh[0]=(bstar<<17)|(sub<<6)|(unsigned)lo;
    }
    __syncthreads();
    unsigned thb=thsh[0];
    for (unsigned c=tid;c<n;c+=256) if (cbits[c]>=thb) atomicAdd(&outr[crow_[c]], ccon[c]);
    __syncthreads();
  }
  float it=inten[s2];
  float t0=x[s2*D+tid]+outr[tid]*it;
  float t1=x[s2*D+tid+256]+outr[tid+256]*it;
  red[tid]=t0+t1; __syncthreads();
  for (int st=128;st>0;st>>=1){ if (tid<st) red[tid]+=red[tid+st]; __syncthreads(); }
  float mean=red[0]*(1.f/512.f); __syncthreads();
  float d0=t0-mean, d1=t1-mean;
  red[tid]=d0*d0+d1*d1; __syncthreads();
  for (int st=128;st>0;st>>=1){ if (tid<st) red[tid]+=red[tid+st]; __syncthreads(); }
  float var=red[0]*(1.f/512.f);
  float rstd=rsqrtf(var+1e-5f);
  co[s2*D+tid]=d0*rstd*n2g[tid]+n2b[tid];
  co[s2*D+tid+256]=d1*rstd*n2g[tid+256]+n2b[tid+256];
}

// ---------------- GEMM: 32x64 tile, LDS-staged, prefetch, 4x2 reg tile ----------------
template<int ACT, int RES>
__global__ void __launch_bounds__(256) k_gemm2(const float* __restrict__ A, const float* __restrict__ W,
    const float* __restrict__ bias, const float* __restrict__ res,
    float* __restrict__ C, int K, int N){
  __shared__ float Ast[32][36];   // [kk][row], row-stride 144B (16B-aligned)
  __shared__ float Ws[32][68];    // [kk][col], row-stride 272B
  int tid=threadIdx.x;
  int cb=blockIdx.x<<6;
  int s0=blockIdx.y<<5;
  int rid=tid>>5;          // 0..7  -> rows rid*4..rid*4+3
  int cid=tid&31;          // cols cid, cid+32
  int arow=tid>>3, akq=tid&7;
  int wrow=tid>>4, wc4=tid&15;
  float acc[4][2]={{0.f,0.f},{0.f,0.f},{0.f,0.f},{0.f,0.f}};
  const float* Aptr = A + (size_t)(s0+arow)*K + (akq<<2);
  const float* Wptr0 = W + (size_t)wrow*N + cb + (wc4<<2);
  const float* Wptr1 = W + (size_t)(wrow+16)*N + cb + (wc4<<2);
  float4 av=*(const float4*)Aptr;
  float4 w0=*(const float4*)Wptr0;
  float4 w1=*(const float4*)Wptr1;
  for (int k0=0;k0<K;k0+=32){
    Ast[(akq<<2)+0][arow]=av.x; Ast[(akq<<2)+1][arow]=av.y;
    Ast[(akq<<2)+2][arow]=av.z; Ast[(akq<<2)+3][arow]=av.w;
    *(float4*)&Ws[wrow][wc4<<2]=w0;
    *(float4*)&Ws[wrow+16][wc4<<2]=w1;
    __syncthreads();
    if (k0+32<K){
      av=*(const float4*)(Aptr + k0+32);
      w0=*(const float4*)(Wptr0 + (size_t)(k0+32)*N);
      w1=*(const float4*)(Wptr1 + (size_t)(k0+32)*N);
    }
    #pragma unroll
    for (int kk=0;kk<32;++kk){
      float4 a4=*(const float4*)&Ast[kk][rid<<2];
      float b0=Ws[kk][cid], b1=Ws[kk][cid+32];
      acc[0][0]=fmaf(a4.x,b0,acc[0][0]); acc[0][1]=fmaf(a4.x,b1,acc[0][1]);
      acc[1][0]=fmaf(a4.y,b0,acc[1][0]); acc[1][1]=fmaf(a4.y,b1,acc[1][1]);
      acc[2][0]=fmaf(a4.z,b0,acc[2][0]); acc[2][1]=fmaf(a4.z,b1,acc[2][1]);
      acc[3][0]=fmaf(a4.w,b0,acc[3][0]); acc[3][1]=fmaf(a4.w,b1,acc[3][1]);
    }
    __syncthreads();
  }
  float bb0=bias[cb+cid], bb1=bias[cb+cid+32];
  #pragma unroll
  for (int r=0;r<4;++r){
    int row=s0+(rid<<2)+r;
    #pragma unroll
    for (int c=0;c<2;++c){
      int col=cb+cid+(c<<5);
      float v=acc[r][c]+(c?bb1:bb0);
      if (ACT==1) v=gelu_f(v);
      if (ACT==2) v=silu_f(v);
      if (RES) v+=res[(size_t)row*N+col];
      C[(size_t)row*N+col]=v;
    }
  }
}

// gated FFN elementwise
__global__ void __launch_bounds__(256) k_gate(const float* __restrict__ ff, float* __restrict__ gv){
  int idx=blockIdx.x*256+threadIdx.x;
  if (idx<S*2048){
    int s2=idx>>11, m=idx&2047;
    float g=ff[s2*4096+m], v=ff[s2*4096+2048+m];
    gv[idx]=silu_f(g)*v;
  }
}

extern "C" void kernel_launch(void* const* d_in, const int* in_sizes, int n_in,
                              void* d_out, int out_size, void* d_ws, size_t ws_size,
                              hipStream_t stream){
  const float* x   =(const float*)d_in[0];
  const float* pat =(const float*)d_in[1];
  const float* sw1 =(const float*)d_in[2];
  const float* sb1 =(const float*)d_in[3];
  const float* sw2 =(const float*)d_in[4];
  const float* sb2 =(const float*)d_in[5];
  const float* ww1 =(const float*)d_in[6];
  const float* wb1 =(const float*)d_in[7];
  const float* ww2 =(const float*)d_in[8];
  const float* wb2 =(const float*)d_in[9];
  const float* iw1 =(const float*)d_in[10];
  const float* ib1 =(const float*)d_in[11];
  const float* iw2 =(const float*)d_in[12];
  const float* ib2 =(const float*)d_in[13];
  const float* mw1 =(const float*)d_in[14];
  const float* mb1 =(const float*)d_in[15];
  const float* mw2 =(const float*)d_in[16];
  const float* mb2 =(const float*)d_in[17];
  const float* bank=(const float*)d_in[18];
  const float* upw =(const float*)d_in[19];
  const float* upb =(const float*)d_in[20];
  const float* dww =(const float*)d_in[21];
  const float* dwb =(const float*)d_in[22];
  const float* n1g =(const float*)d_in[23];
  const float* n1b =(const float*)d_in[24];
  const float* n2g =(const float*)d_in[25];
  const float* n2b =(const float*)d_in[26];
  float* out=(float*)d_out;

  float* w = (float*)d_ws;
  float* xn     = w;                 // 131072
  float* xr     = xn+131072;
  float* meanxr = xr+131072;         // 512
  float* memmean= meanxr+512;        // 512
  float* pwb    = memmean+512;       // 4096
  float* inten  = pwb+4096;          // 256
  float* ctxsel = inten+256;         // 32
  float* ctxint = ctxsel+32;         // 64
  float* mempart= ctxint+64;         // 512
  float* co     = mempart+512;       // 131072
  float* h1     = co+131072;         // 131072
  float* co2    = h1+131072;         // 131072
  float* ff     = co2+131072;        // 1048576
  float* gv     = ff+1048576;        // 524288
  int*   kkp    = (int*)(gv+524288);
  unsigned* meta= (unsigned*)(kkp+4);  // 256*3
  float* flow   = (float*)(meta+768+256);   // aligned enough (offset multiple of 4 floats; base 256B-aligned region)

  size_t small_floats = (size_t)((char*)flow - (char*)d_ws)/4;
  size_t need_bytes = (small_floats + (size_t)67108864)*4;
  bool fast = ws_size >= need_bytes;

  k_ln_rope<<<S,256,0,stream>>>(x,n1g,n1b,xn,xr);
  k_colmean<<<4,256,0,stream>>>(xr,bank,meanxr,memmean);
  k_head<<<1,256,0,stream>>>(meanxr,memmean,ww1,wb1,ww2,wb2,sw1,sb1,iw1,ib1,mw1,mb1,
                             ctxsel,ctxint,mempart,kkp);
  k_selint<<<S,256,0,stream>>>(xr,ctxsel,ctxint,sw1,sw2,sb2,iw1,iw2,ib2,pwb,inten);
  if (fast){
    k_flow_store<<<dim3(32,32),256,0,stream>>>(pat,pwb,flow);
    k_topk<<<S,256,0,stream>>>(flow,xn,x,inten,kkp,n2g,n2b,co);
  } else {
    k_hist<<<S,256,0,stream>>>(pat,pwb,kkp,meta);
    k_select<<<S,256,0,stream>>>(pat,pwb,xn,x,inten,meta,n2g,n2b,co);
  }
  k_gemm2<2,0><<<dim3(8,8),256,0,stream>>>(co, mw1, mempart, nullptr, h1, 512, 512);
  k_gemm2<0,1><<<dim3(8,8),256,0,stream>>>(h1, mw2, mb2, co, co2, 512, 512);
  k_gemm2<0,0><<<dim3(64,8),256,0,stream>>>(co2, upw, upb, nullptr, ff, 512, 4096);
  k_gate<<<2048,256,0,stream>>>(ff,gv);
  k_gemm2<0,1><<<dim3(8,8),256,0,stream>>>(gv, dww, dwb, co2, out, 2048, 512);
}

// Round 5
// 672.580 us; speedup vs baseline: 2.9409x; 1.6251x over previous
//
#include <hip/hip_runtime.h>
#include <math.h>

#define S 256
#define D 512
#define P 16
#define NIJ (D*D)
#define CAP 4096

__device__ __forceinline__ float gelu_f(float x){ return 0.5f*x*(1.f+erff(x*0.70710678118654752f)); }
__device__ __forceinline__ float silu_f(float x){ return x/(1.f+expf(-x)); }
__device__ __forceinline__ float sigm_f(float x){ return 1.f/(1.f+expf(-x)); }

// v[0..3] = flow values at linear elements e..e+3 (e multiple of 4): sum_p pw[p]*pat[p][e]
__device__ __forceinline__ void flow4(const float4* __restrict__ patv, const float* pws,
                                      int e, float v[4]){
  int base = e >> 2;
  float4 a = make_float4(0.f,0.f,0.f,0.f);
  #pragma unroll
  for (int p2=0;p2<16;++p2){
    float4 pv = patv[base + (p2<<16)];
    float w = pws[p2];
    a.x=fmaf(w,pv.x,a.x); a.y=fmaf(w,pv.y,a.y); a.z=fmaf(w,pv.z,a.z); a.w=fmaf(w,pv.w,a.w);
  }
  v[0]=a.x; v[1]=a.y; v[2]=a.z; v[3]=a.w;
}

// K1: LayerNorm + RoPE per row
__global__ void __launch_bounds__(256) k_ln_rope(const float* __restrict__ x,
    const float* __restrict__ g, const float* __restrict__ b,
    float* __restrict__ xn, float* __restrict__ xr){
  int s2 = blockIdx.x, tid = threadIdx.x;
  __shared__ float red[256];
  __shared__ float xnl[512];
  const float* xrow = x + s2*D;
  float v0 = xrow[tid], v1 = xrow[tid+256];
  red[tid] = v0+v1; __syncthreads();
  for (int st=128; st>0; st>>=1){ if (tid<st) red[tid]+=red[tid+st]; __syncthreads(); }
  float mean = red[0]*(1.f/512.f); __syncthreads();
  float d0=v0-mean, d1=v1-mean;
  red[tid]=d0*d0+d1*d1; __syncthreads();
  for (int st=128; st>0; st>>=1){ if (tid<st) red[tid]+=red[tid+st]; __syncthreads(); }
  float var = red[0]*(1.f/512.f);
  float rstd = rsqrtf(var+1e-5f);
  float a0 = d0*rstd*g[tid]+b[tid];
  float a1 = d1*rstd*g[tid+256]+b[tid+256];
  xn[s2*D+tid]=a0; xn[s2*D+tid+256]=a1;
  xnl[tid]=a0; xnl[tid+256]=a1;
  __syncthreads();
  int j = tid;
  float e = (float)(2*j)*(1.f/512.f);
  float inv = 1.f/powf(10000.f, e);
  float ang = (float)s2 * inv;
  float c = cosf(ang), sn = sinf(ang);
  float p0 = xnl[2*j], p1 = xnl[2*j+1];
  xr[s2*D+2*j]   = p0*c - p1*sn;
  xr[s2*D+2*j+1] = p1*c + p0*sn;
}

// K2: column means
__global__ void __launch_bounds__(256) k_colmean(const float* __restrict__ xr,
    const float* __restrict__ bank, float* __restrict__ meanxr, float* __restrict__ memmean){
  int tid=threadIdx.x;
  if (blockIdx.x<2){
    int d2 = blockIdx.x*256+tid; float acc=0.f;
    for (int s2=0;s2<S;++s2) acc += xr[s2*D+d2];
    meanxr[d2]=acc*(1.f/256.f);
  } else {
    int d2=(blockIdx.x-2)*256+tid; float acc=0.f;
    for (int r=0;r<512;++r) acc += bank[r*D+d2];
    memmean[d2]=acc*(1.f/512.f);
  }
}

// K3: window MLP -> kk; fold ctx/mem halves into effective biases
__global__ void __launch_bounds__(256) k_head(const float* __restrict__ meanxr, const float* __restrict__ memmean,
    const float* __restrict__ ww1, const float* __restrict__ wb1,
    const float* __restrict__ ww2, const float* __restrict__ wb2,
    const float* __restrict__ sw1, const float* __restrict__ sb1,
    const float* __restrict__ iw1, const float* __restrict__ ib1,
    const float* __restrict__ mw1, const float* __restrict__ mb1,
    float* __restrict__ ctxsel, float* __restrict__ ctxint,
    float* __restrict__ mempart, int* __restrict__ kkout){
  int tid=threadIdx.x;
  __shared__ float mx[512], mm[512], gw[64];
  mx[tid]=meanxr[tid]; mx[tid+256]=meanxr[tid+256];
  mm[tid]=memmean[tid]; mm[tid+256]=memmean[tid+256];
  __syncthreads();
  if (tid<64){ float a=wb1[tid]; for (int d2=0;d2<512;++d2) a=fmaf(mx[d2], ww1[d2*64+tid], a); gw[tid]=gelu_f(a); }
  __syncthreads();
  if (tid==0){
    float a=wb2[0]; for (int h=0;h<64;++h) a=fmaf(gw[h], ww2[h], a);
    float win = sigm_f(a)*3840.f+256.f;
    float asp = 0.1f*(win*(1.f/4096.f));
    float t = 262144.f*asp;
    int kk=(int)t; if (kk<1) kk=1;
    *kkout=kk;
  }
  if (tid<32){ float a=sb1[tid]; for (int d2=0;d2<512;++d2) a=fmaf(mx[d2], sw1[(512+d2)*32+tid], a); ctxsel[tid]=a; }
  if (tid>=64 && tid<128){ int o=tid-64; float a=ib1[o]; for (int d2=0;d2<512;++d2) a=fmaf(mx[d2], iw1[(512+d2)*64+o], a); ctxint[o]=a; }
  for (int o=tid;o<512;o+=256){ float a=mb1[o]; for (int d2=0;d2<512;++d2) a=fmaf(mm[d2], mw1[(512+d2)*512+o], a); mempart[o]=a; }
}

// K4: per-position selection MLP (softmax pw) + intensity
__global__ void __launch_bounds__(256) k_selint(const float* __restrict__ xr,
    const float* __restrict__ ctxsel, const float* __restrict__ ctxint,
    const float* __restrict__ sw1, const float* __restrict__ sw2, const float* __restrict__ sb2,
    const float* __restrict__ iw1, const float* __restrict__ iw2, const float* __restrict__ ib2,
    float* __restrict__ pw, float* __restrict__ inten){
  int s2=blockIdx.x, tid=threadIdx.x;
  __shared__ float xl[512]; __shared__ float h1[32], h2[64], lg[16];
  xl[tid]=xr[s2*D+tid]; xl[tid+256]=xr[s2*D+tid+256];
  __syncthreads();
  if (tid<32){ float a=ctxsel[tid]; for (int d2=0;d2<512;++d2) a=fmaf(xl[d2], sw1[d2*32+tid], a); h1[tid]=gelu_f(a); }
  else if (tid<96){ int o=tid-32; float a=ctxint[o]; for (int d2=0;d2<512;++d2) a=fmaf(xl[d2], iw1[d2*64+o], a); h2[o]=gelu_f(a); }
  __syncthreads();
  if (tid<16){ float a=sb2[tid]; for (int h=0;h<32;++h) a=fmaf(h1[h], sw2[h*16+tid], a); lg[tid]=a; }
  __syncthreads();
  if (tid==0){
    float m=lg[0]; for (int p2=1;p2<16;++p2) m=fmaxf(m,lg[p2]);
    float sm=0.f; float e[16];
    for (int p2=0;p2<16;++p2){ e[p2]=expf(lg[p2]-m); sm+=e[p2]; }
    float r=1.f/sm;
    for (int p2=0;p2<16;++p2) pw[s2*16+p2]=e[p2]*r;
  }
  if (tid==64){ float a=ib2[0]; for (int h=0;h<64;++h) a=fmaf(h2[h], iw2[h], a); inten[s2]=sigm_f(a); }
}

// K5: fused histogram + exact radix-select + masked matvec + residual + LN2.
// 1024 threads/block (4 waves/SIMD) to hide pattern-load latency.
__global__ void __launch_bounds__(1024) k_flowsel(const float* __restrict__ pat,
    const float* __restrict__ pw, const float* __restrict__ xn, const float* __restrict__ x,
    const float* __restrict__ inten, const int* __restrict__ kkin,
    const float* __restrict__ n2g, const float* __restrict__ n2b,
    float* __restrict__ co){
  int s2=blockIdx.x, tid=threadIdx.x;
  __shared__ unsigned hist[16384];   // 64KB; reused: cbits[0..4095] | ccon[4096..8191] | crow u16 @8192
  __shared__ float xnl[512], outr[512], red[512];
  __shared__ float pws[16];
  __shared__ unsigned part[1024];
  __shared__ unsigned sup[64];
  __shared__ unsigned rhist[2048];
  __shared__ unsigned rpart[128];
  __shared__ unsigned thsh[4];
  __shared__ unsigned ccount;
  if (tid<512) xnl[tid]=xn[s2*D+tid];
  if (tid<16) pws[tid]=pw[s2*16+tid];
  if (tid==0) ccount=0u;
  for (int i=tid;i<16384;i+=1024) hist[i]=0u;
  __syncthreads();
  const float4* patv=(const float4*)pat;
  // phase A: 14-bit prefix histogram over all 262144 flow values
  for (int it=0; it<64; ++it){
    int e=(((it<<10)+tid)<<2);
    float v[4]; flow4(patv,pws,e,v);
    #pragma unroll
    for (int q=0;q<4;++q)
      atomicAdd(&hist[(__float_as_uint(v[q])&0x7fffffffu)>>17],1u);
  }
  __syncthreads();
  // hierarchical scan: 16384 -> 1024 -> 64
  { unsigned ps=0;
    #pragma unroll
    for (int k2=0;k2<16;++k2) ps+=hist[tid*16+k2];
    part[tid]=ps; }
  __syncthreads();
  if (tid<64){ unsigned t=0;
    #pragma unroll
    for (int k2=0;k2<16;++k2) t+=part[tid*16+k2];
    sup[tid]=t; }
  __syncthreads();
  if (tid==0){
    unsigned kk=(unsigned)(*kkin);
    unsigned cum=0; int sj=0;
    for (int j=63;j>=0;--j){ if (cum+sup[j]>=kk){ sj=j; break; } cum+=sup[j]; }
    int pi=sj*16;
    for (int j=sj*16+15;j>=sj*16;--j){ if (cum+part[j]>=kk){ pi=j; break; } cum+=part[j]; }
    int bst=pi*16;
    for (int b2=pi*16+15;b2>=pi*16;--b2){ if (cum+hist[b2]>=kk){ bst=b2; break; } cum+=hist[b2]; }
    thsh[0]=(unsigned)bst; thsh[1]=kk-cum; thsh[2]=hist[bst];
  }
  __syncthreads();
  unsigned bstar=thsh[0], rnk=thsh[1], cnt=thsh[2];
  bool incl = cnt>CAP;     // pathological fallback: keep whole bin
  __syncthreads();
  // phase B: masked matvec + candidate stash (reuses hist region)
  unsigned* cbits=hist; float* ccon=(float*)(hist+4096);
  unsigned short* crow_=(unsigned short*)(hist+8192);
  int wave=tid>>6, lane=tid&63;
  for (int i=wave;i<512;i+=16){
    float acc=0.f;
    #pragma unroll
    for (int jc=0;jc<2;++jc){
      int j=(lane<<2)+(jc<<8);
      float v[4]; flow4(patv,pws,(i<<9)+j,v);
      #pragma unroll
      for (int q=0;q<4;++q){
        unsigned bits=__float_as_uint(v[q])&0x7fffffffu;
        unsigned pfx=bits>>17;
        if (pfx>bstar || (incl && pfx==bstar)) acc=fmaf(v[q], xnl[j+q], acc);
        else if (pfx==bstar){
          unsigned idx=atomicAdd(&ccount,1u);
          if (idx<CAP){ cbits[idx]=bits; ccon[idx]=v[q]*xnl[j+q]; crow_[idx]=(unsigned short)i; }
        }
      }
    }
    #pragma unroll
    for (int m=32;m>0;m>>=1) acc += __shfl_xor(acc, m, 64);
    if (lane==0) outr[i]=acc;
  }
  __syncthreads();
  if (!incl){
    unsigned n=ccount; if (n>CAP) n=CAP;
    for (int i=tid;i<2048;i+=1024) rhist[i]=0u;
    __syncthreads();
    for (unsigned c2=tid;c2<n;c2+=1024) atomicAdd(&rhist[(cbits[c2]>>6)&0x7ffu],1u);
    __syncthreads();
    if (tid<128){ unsigned t=0;
      #pragma unroll
      for (int k2=0;k2<16;++k2) t+=rhist[tid*16+k2];
      rpart[tid]=t; }
    __syncthreads();
    if (tid==0){
      unsigned cum=0; int rp=0;
      for (int j=127;j>=0;--j){ if (cum+rpart[j]>=rnk){ rp=j; break; } cum+=rpart[j]; }
      int sub=rp*16;
      for (int b2=rp*16+15;b2>=rp*16;--b2){ if (cum+rhist[b2]>=rnk){ sub=b2; break; } cum+=rhist[b2]; }
      thsh[0]=(unsigned)sub; thsh[1]=rnk-cum;
    }
    __syncthreads();
    unsigned sub=thsh[0], r2=thsh[1];
    if (tid<64) rhist[tid]=0u;
    __syncthreads();
    for (unsigned c2=tid;c2<n;c2+=1024) if (((cbits[c2]>>6)&0x7ffu)==sub) atomicAdd(&rhist[cbits[c2]&63u],1u);
    __syncthreads();
    if (tid==0){
      unsigned cum=0; unsigned lo=0;
      for (int b2=63;b2>=0;--b2){ if (cum+rhist[b2]>=r2){ lo=(unsigned)b2; break; } cum+=rhist[b2]; }
      thsh[2]=(bstar<<17)|(sub<<6)|lo;
    }
    __syncthreads();
    unsigned thb=thsh[2];
    for (unsigned c2=tid;c2<n;c2+=1024) if (cbits[c2]>=thb) atomicAdd(&outr[crow_[c2]], ccon[c2]);
  }
  __syncthreads();
  // residual + LN2
  float it=inten[s2];
  float t0=0.f;
  if (tid<512){ t0=x[s2*D+tid]+outr[tid]*it; red[tid]=t0; }
  __syncthreads();
  for (int st=256;st>0;st>>=1){ if (tid<st) red[tid]+=red[tid+st]; __syncthreads(); }
  float mean=red[0]*(1.f/512.f); __syncthreads();
  float d0=t0-mean;
  if (tid<512) red[tid]=d0*d0;
  __syncthreads();
  for (int st=256;st>0;st>>=1){ if (tid<st) red[tid]+=red[tid+st]; __syncthreads(); }
  float var=red[0]*(1.f/512.f);
  float rstd=rsqrtf(var+1e-5f);
  if (tid<512) co[s2*D+tid]=d0*rstd*n2g[tid]+n2b[tid];
}

// ---------------- GEMM: 32x64 tile, LDS-staged, prefetch, 4x2 reg tile ----------------
template<int ACT, int RES>
__global__ void __launch_bounds__(256) k_gemm2(const float* __restrict__ A, const float* __restrict__ W,
    const float* __restrict__ bias, const float* __restrict__ res,
    float* __restrict__ C, int K, int N){
  __shared__ float Ast[32][36];
  __shared__ float Ws[32][68];
  int tid=threadIdx.x;
  int cb=blockIdx.x<<6;
  int s0=blockIdx.y<<5;
  int rid=tid>>5;
  int cid=tid&31;
  int arow=tid>>3, akq=tid&7;
  int wrow=tid>>4, wc4=tid&15;
  float acc[4][2]={{0.f,0.f},{0.f,0.f},{0.f,0.f},{0.f,0.f}};
  const float* Aptr = A + (size_t)(s0+arow)*K + (akq<<2);
  const float* Wptr0 = W + (size_t)wrow*N + cb + (wc4<<2);
  const float* Wptr1 = W + (size_t)(wrow+16)*N + cb + (wc4<<2);
  float4 av=*(const float4*)Aptr;
  float4 w0=*(const float4*)Wptr0;
  float4 w1=*(const float4*)Wptr1;
  for (int k0=0;k0<K;k0+=32){
    Ast[(akq<<2)+0][arow]=av.x; Ast[(akq<<2)+1][arow]=av.y;
    Ast[(akq<<2)+2][arow]=av.z; Ast[(akq<<2)+3][arow]=av.w;
    *(float4*)&Ws[wrow][wc4<<2]=w0;
    *(float4*)&Ws[wrow+16][wc4<<2]=w1;
    __syncthreads();
    if (k0+32<K){
      av=*(const float4*)(Aptr + k0+32);
      w0=*(const float4*)(Wptr0 + (size_t)(k0+32)*N);
      w1=*(const float4*)(Wptr1 + (size_t)(k0+32)*N);
    }
    #pragma unroll
    for (int kk=0;kk<32;++kk){
      float4 a4=*(const float4*)&Ast[kk][rid<<2];
      float b0=Ws[kk][cid], b1=Ws[kk][cid+32];
      acc[0][0]=fmaf(a4.x,b0,acc[0][0]); acc[0][1]=fmaf(a4.x,b1,acc[0][1]);
      acc[1][0]=fmaf(a4.y,b0,acc[1][0]); acc[1][1]=fmaf(a4.y,b1,acc[1][1]);
      acc[2][0]=fmaf(a4.z,b0,acc[2][0]); acc[2][1]=fmaf(a4.z,b1,acc[2][1]);
      acc[3][0]=fmaf(a4.w,b0,acc[3][0]); acc[3][1]=fmaf(a4.w,b1,acc[3][1]);
    }
    __syncthreads();
  }
  float bb0=bias[cb+cid], bb1=bias[cb+cid+32];
  #pragma unroll
  for (int r=0;r<4;++r){
    int row=s0+(rid<<2)+r;
    #pragma unroll
    for (int c=0;c<2;++c){
      int col=cb+cid+(c<<5);
      float v=acc[r][c]+(c?bb1:bb0);
      if (ACT==1) v=gelu_f(v);
      if (ACT==2) v=silu_f(v);
      if (RES) v+=res[(size_t)row*N+col];
      C[(size_t)row*N+col]=v;
    }
  }
}

// gated FFN elementwise
__global__ void __launch_bounds__(256) k_gate(const float* __restrict__ ff, float* __restrict__ gv){
  int idx=blockIdx.x*256+threadIdx.x;
  if (idx<S*2048){
    int s2=idx>>11, m=idx&2047;
    float g=ff[s2*4096+m], v=ff[s2*4096+2048+m];
    gv[idx]=silu_f(g)*v;
  }
}

extern "C" void kernel_launch(void* const* d_in, const int* in_sizes, int n_in,
                              void* d_out, int out_size, void* d_ws, size_t ws_size,
                              hipStream_t stream){
  const float* x   =(const float*)d_in[0];
  const float* pat =(const float*)d_in[1];
  const float* sw1 =(const float*)d_in[2];
  const float* sb1 =(const float*)d_in[3];
  const float* sw2 =(const float*)d_in[4];
  const float* sb2 =(const float*)d_in[5];
  const float* ww1 =(const float*)d_in[6];
  const float* wb1 =(const float*)d_in[7];
  const float* ww2 =(const float*)d_in[8];
  const float* wb2 =(const float*)d_in[9];
  const float* iw1 =(const float*)d_in[10];
  const float* ib1 =(const float*)d_in[11];
  const float* iw2 =(const float*)d_in[12];
  const float* ib2 =(const float*)d_in[13];
  const float* mw1 =(const float*)d_in[14];
  const float* mb1 =(const float*)d_in[15];
  const float* mw2 =(const float*)d_in[16];
  const float* mb2 =(const float*)d_in[17];
  const float* bank=(const float*)d_in[18];
  const float* upw =(const float*)d_in[19];
  const float* upb =(const float*)d_in[20];
  const float* dww =(const float*)d_in[21];
  const float* dwb =(const float*)d_in[22];
  const float* n1g =(const float*)d_in[23];
  const float* n1b =(const float*)d_in[24];
  const float* n2g =(const float*)d_in[25];
  const float* n2b =(const float*)d_in[26];
  float* out=(float*)d_out;

  float* w = (float*)d_ws;
  float* xn     = w;                 // 131072
  float* xr     = xn+131072;
  float* meanxr = xr+131072;         // 512
  float* memmean= meanxr+512;        // 512
  float* pwb    = memmean+512;       // 4096
  float* inten  = pwb+4096;          // 256
  float* ctxsel = inten+256;         // 32
  float* ctxint = ctxsel+32;         // 64
  float* mempart= ctxint+64;         // 512
  float* co     = mempart+512;       // 131072
  float* h1     = co+131072;         // 131072
  float* co2    = h1+131072;         // 131072
  float* ff     = co2+131072;        // 1048576
  float* gv     = ff+1048576;        // 524288
  int*   kkp    = (int*)(gv+524288);

  k_ln_rope<<<S,256,0,stream>>>(x,n1g,n1b,xn,xr);
  k_colmean<<<4,256,0,stream>>>(xr,bank,meanxr,memmean);
  k_head<<<1,256,0,stream>>>(meanxr,memmean,ww1,wb1,ww2,wb2,sw1,sb1,iw1,ib1,mw1,mb1,
                             ctxsel,ctxint,mempart,kkp);
  k_selint<<<S,256,0,stream>>>(xr,ctxsel,ctxint,sw1,sw2,sb2,iw1,iw2,ib2,pwb,inten);
  k_flowsel<<<S,1024,0,stream>>>(pat,pwb,xn,x,inten,kkp,n2g,n2b,co);
  k_gemm2<2,0><<<dim3(8,8),256,0,stream>>>(co, mw1, mempart, nullptr, h1, 512, 512);
  k_gemm2<0,1><<<dim3(8,8),256,0,stream>>>(h1, mw2, mb2, co, co2, 512, 512);
  k_gemm2<0,0><<<dim3(64,8),256,0,stream>>>(co2, upw, upb, nullptr, ff, 512, 4096);
  k_gate<<<2048,256,0,stream>>>(ff,gv);
  k_gemm2<0,1><<<dim3(8,8),256,0,stream>>>(gv, dww, dwb, co2, out, 2048, 512);
}